// Round 5
// baseline (271.181 us; speedup 1.0000x reference)
//
#include <hip/hip_runtime.h>

#define IN_F   128
#define OUTD   64
#define HOUT   256      // H*OUT
#define NEG_SLOPE 0.2f
#define BN_EPS 1e-5f
#define HIST_BLOCKS 512
#define BPAD 136        // 128 + 8 shorts pad

typedef __attribute__((ext_vector_type(8))) short bf16x8;
typedef __attribute__((ext_vector_type(4))) float f32x4;
typedef __attribute__((ext_vector_type(2))) float f32x2;

__device__ __forceinline__ unsigned short f2bf(float f) {
    union { float f; unsigned u; } v; v.f = f;
    unsigned r = (v.u + 0x7FFF + ((v.u >> 16) & 1)) >> 16;   // RNE
    return (unsigned short)r;
}
__device__ __forceinline__ float bf2f(unsigned short h) {
    union { unsigned u; float f; } v; v.u = ((unsigned)h) << 16;
    return v.f;
}

// ============ K0: pack W_fc|W_gres|W_res -> Btg[576][128] bf16 (k-contig) ============
__global__ __launch_bounds__(256) void k0_pack(
    const float* __restrict__ W_fc, const float* __restrict__ W_gres,
    const float* __restrict__ W_res, unsigned short* __restrict__ Btg)
{
    int idx = blockIdx.x * 256 + threadIdx.x;   // idx = c*128 + k
    if (idx >= 576 * 128) return;
    int c = idx >> 7, k = idx & 127;
    float v;
    if (c < 256)      v = W_fc[k * HOUT + c];
    else if (c < 512) v = W_gres[k * HOUT + (c - 256)];
    else              v = W_res[k * OUTD + (c - 512)];
    Btg[idx] = f2bf(v);
}

// ============ K1: MFMA GEMM (64-row m-tiles, loop 9 n-tiles) + hist + el/er ============
// outputs: Hh8 fp8 [r][d][head] (256 B/row) ; Hr8 fp8 gat_res+bias same layout ;
//          Rres bf16 [r][d] (outer residual) ; el/er fp32 [r][4]
__global__ __launch_bounds__(256) void k1_gemm(
    const float* __restrict__ A, const unsigned short* __restrict__ Btg,
    const float* __restrict__ attn_l, const float* __restrict__ attn_r,
    const float* __restrict__ gat_bias, const float* __restrict__ res_b,
    const int* __restrict__ dst, int* __restrict__ degree, int* __restrict__ rank,
    unsigned char* __restrict__ Hh8, unsigned char* __restrict__ Hr8,
    unsigned short* __restrict__ Rres,
    float* __restrict__ el, float* __restrict__ er,
    int N, int E, int Mtiles)
{
    __shared__ __align__(16) unsigned short As[64 * BPAD];
    __shared__ __align__(16) unsigned short Bs[64 * BPAD];
    int bid = blockIdx.x, t = threadIdx.x;

    if (bid >= Mtiles) {   // histogram blocks, concurrent with GEMM blocks
        int hb = bid - Mtiles;
        for (int e = hb * 256 + t; e < E; e += HIST_BLOCKS * 256)
            rank[e] = atomicAdd(degree + dst[e], 1);
        return;
    }

    int m0 = bid * 64;

    // stage A tile: 64 rows x 128 k, fp32 -> bf16 in-register
    for (int i = 0; i < 8; ++i) {
        int slot = t + i * 256;            // 0..2047
        int r = slot >> 5, c4 = (slot & 31) << 2;
        float4 v = make_float4(0.f, 0.f, 0.f, 0.f);
        if (m0 + r < N) v = *(const float4*)(A + (size_t)(m0 + r) * IN_F + c4);
        ushort4 o;
        o.x = f2bf(v.x); o.y = f2bf(v.y); o.z = f2bf(v.z); o.w = f2bf(v.w);
        *(ushort4*)(&As[r * BPAD + c4]) = o;
    }

    int w = t >> 6, lane = t & 63, quad = lane >> 4, n15 = lane & 15;
    bf16x8 af[4];
    unsigned hpack[4][4] = {};    // [j][reg] Hh8 bytes
    unsigned rpack[4][4] = {};    // [j][reg] Hr8 bytes

    for (int n = 0; n < 9; ++n) {
        if (n) __syncthreads();
        for (int i = 0; i < 4; ++i) {     // B tile: 64 cols x 128 k
            int slot = t + i * 256;
            int c = slot >> 4, k0 = (slot & 15) << 3;
            *(uint4*)(&Bs[c * BPAD + k0]) = *(const uint4*)(Btg + (size_t)(n * 64 + c) * IN_F + k0);
        }
        __syncthreads();
        if (n == 0) {
#pragma unroll
            for (int ks = 0; ks < 4; ++ks)
                af[ks] = *(const bf16x8*)(&As[(w * 16 + n15) * BPAD + ks * 32 + quad * 8]);
        }

        f32x4 acc[4] = {};
#pragma unroll
        for (int ks = 0; ks < 4; ++ks) {
            bf16x8 bfr[4];
#pragma unroll
            for (int j = 0; j < 4; ++j)
                bfr[j] = *(const bf16x8*)(&Bs[(j * 16 + n15) * BPAD + ks * 32 + quad * 8]);
#pragma unroll
            for (int j = 0; j < 4; ++j)
                acc[j] = __builtin_amdgcn_mfma_f32_16x16x32_bf16(af[ks], bfr[j], acc[j], 0, 0, 0);
        }

        if (n < 4) {
            // ---- el/er ----
            float alv[4], arv[4];
#pragma unroll
            for (int j = 0; j < 4; ++j) {
                alv[j] = attn_l[n * 64 + j * 16 + n15];
                arv[j] = attn_r[n * 64 + j * 16 + n15];
            }
#pragma unroll
            for (int reg = 0; reg < 4; ++reg) {
                float pl = acc[0][reg] * alv[0] + acc[1][reg] * alv[1]
                         + acc[2][reg] * alv[2] + acc[3][reg] * alv[3];
                float pr = acc[0][reg] * arv[0] + acc[1][reg] * arv[1]
                         + acc[2][reg] * arv[2] + acc[3][reg] * arv[3];
#pragma unroll
                for (int off = 1; off < 16; off <<= 1) {
                    pl += __shfl_xor(pl, off);
                    pr += __shfl_xor(pr, off);
                }
                int r = m0 + w * 16 + quad * 4 + reg;
                if (n15 == 0 && r < N) {
                    el[(size_t)r * 4 + n] = pl;
                    er[(size_t)r * 4 + n] = pr;
                }
            }
            // ---- pack Hh fp8 (head n) ----
#pragma unroll
            for (int j = 0; j < 4; ++j)
#pragma unroll
                for (int reg = 0; reg < 4; ++reg) {
                    float v = acc[j][reg];
                    unsigned pk = (unsigned)__builtin_amdgcn_cvt_pk_fp8_f32(v, v, 0, false);
                    hpack[j][reg] |= (pk & 0xffu) << (8 * n);
                }
        } else if (n < 8) {
            // ---- pack Hr fp8 (gat_res + bias, head n-4) ----
            int hd = n - 4;
            float bv[4];
#pragma unroll
            for (int j = 0; j < 4; ++j) bv[j] = gat_bias[hd * 64 + j * 16 + n15];
#pragma unroll
            for (int j = 0; j < 4; ++j)
#pragma unroll
                for (int reg = 0; reg < 4; ++reg) {
                    float v = acc[j][reg] + bv[j];
                    unsigned pk = (unsigned)__builtin_amdgcn_cvt_pk_fp8_f32(v, v, 0, false);
                    rpack[j][reg] |= (pk & 0xffu) << (8 * hd);
                }
        } else {
            // ---- Rres bf16 (outer residual + res_b) ----
            float bv[4];
#pragma unroll
            for (int j = 0; j < 4; ++j) bv[j] = res_b[j * 16 + n15];
#pragma unroll
            for (int reg = 0; reg < 4; ++reg) {
                int r = m0 + w * 16 + quad * 4 + reg;
                if (r < N) {
#pragma unroll
                    for (int j = 0; j < 4; ++j)
                        Rres[(size_t)r * OUTD + j * 16 + n15] = f2bf(acc[j][reg] + bv[j]);
                }
            }
        }
    }

    // ---- store packed fp8 Hh8 / Hr8 (coalesced dwords) ----
#pragma unroll
    for (int reg = 0; reg < 4; ++reg) {
        int r = m0 + w * 16 + quad * 4 + reg;
        if (r < N) {
#pragma unroll
            for (int j = 0; j < 4; ++j) {
                *(unsigned*)(Hh8 + ((size_t)r << 8) + (j * 16 + n15) * 4) = hpack[j][reg];
                *(unsigned*)(Hr8 + ((size_t)r << 8) + (j * 16 + n15) * 4) = rpack[j][reg];
            }
        }
    }
}

// ============ hierarchical scan ============
__global__ __launch_bounds__(256) void scanA_kernel(const int* __restrict__ degree,
                                                    int* __restrict__ excl,
                                                    int* __restrict__ blocksum, int N) {
    __shared__ int sm[256];
    int t = threadIdx.x;
    int i = blockIdx.x * 256 + t;
    int d = (i < N) ? degree[i] : 0;
    sm[t] = d; __syncthreads();
    for (int off = 1; off < 256; off <<= 1) {
        int v = (t >= off) ? sm[t - off] : 0;
        __syncthreads();
        sm[t] += v;
        __syncthreads();
    }
    if (i < N) excl[i] = sm[t] - d;
    if (t == 255) blocksum[blockIdx.x] = sm[255];
}

__global__ __launch_bounds__(256) void scanB_kernel(const int* __restrict__ blocksum,
                                                    int* __restrict__ base, int nb) {
    __shared__ int sm[256];
    int t = threadIdx.x;
    int d = (t < nb) ? blocksum[t] : 0;
    sm[t] = d; __syncthreads();
    for (int off = 1; off < 256; off <<= 1) {
        int v = (t >= off) ? sm[t - off] : 0;
        __syncthreads();
        sm[t] += v;
        __syncthreads();
    }
    if (t < nb) base[t] = sm[t] - d;
}

// ============ scatter + edge-score: es_sorted[p] = {u*256, s01, s23, 0} ============
__global__ void scatter_kernel(const int* __restrict__ src, const int* __restrict__ dst,
                               const int* __restrict__ rank, const int* __restrict__ excl,
                               const int* __restrict__ base,
                               const float* __restrict__ el, const float* __restrict__ er,
                               uint4* __restrict__ es_sorted, int E) {
    int e = blockIdx.x * 256 + threadIdx.x;
    if (e >= E) return;
    int d = dst[e], u = src[e];
    int p = excl[d] + base[d >> 8] + rank[e];
    float4 l = *(const float4*)(el + (size_t)u * 4);
    float4 r = *(const float4*)(er + (size_t)d * 4);
    float x, s0, s1, s2, s3;
    x = l.x + r.x; x = x > 0.f ? x : NEG_SLOPE * x; s0 = __expf(x);
    x = l.y + r.y; x = x > 0.f ? x : NEG_SLOPE * x; s1 = __expf(x);
    x = l.z + r.z; x = x > 0.f ? x : NEG_SLOPE * x; s2 = __expf(x);
    x = l.w + r.w; x = x > 0.f ? x : NEG_SLOPE * x; s3 = __expf(x);
    uint4 o;
    o.x = (unsigned)u << 8;   // pre-scaled byte offset into Hh8
    o.y = (unsigned)f2bf(s0) | ((unsigned)f2bf(s1) << 16);
    o.z = (unsigned)f2bf(s2) | ((unsigned)f2bf(s3) << 16);
    o.w = 0u;
    es_sorted[p] = o;
}

// ============ aggregation + epilogue: readlane broadcast, zero DS-pipe inner loop ============
__global__ __launch_bounds__(256) void agg_kernel(
    const unsigned char* __restrict__ Hh8, const unsigned char* __restrict__ Hr8,
    const unsigned short* __restrict__ Rres,
    const int* __restrict__ excl, const int* __restrict__ base,
    const uint4* __restrict__ es_sorted,
    const float* __restrict__ conv_w, const float* __restrict__ conv_b,
    float* __restrict__ y, int N, int E)
{
    int wave = threadIdx.x >> 6, lane = threadIdx.x & 63;
    int v = blockIdx.x * 4 + wave;
    if (v >= N) return;
    int b  = excl[v] + base[v >> 8];
    int e2 = (v + 1 < N) ? (excl[v + 1] + base[(v + 1) >> 8]) : E;
    int deg = e2 - b;

    const unsigned char* hbase = Hh8 + lane * 4;
    float a0 = 0.f, a1 = 0.f, a2 = 0.f, a3 = 0.f;
    float p0 = 0.f, p1 = 0.f, p2 = 0.f, p3 = 0.f;

    for (int i0 = 0; i0 < deg; i0 += 64) {
        int j = i0 + lane;
        uint4 es = make_uint4(0u, 0u, 0u, 0u);
        if (j < deg) es = es_sorted[b + j];
        p0 += bf2f((unsigned short)(es.y & 0xffff));
        p1 += bf2f((unsigned short)(es.y >> 16));
        p2 += bf2f((unsigned short)(es.z & 0xffff));
        p3 += bf2f((unsigned short)(es.z >> 16));
        int cl = deg - i0; if (cl > 64) cl = 64;
        int jj = 0;
        for (; jj + 1 < cl; jj += 2) {
            unsigned uA   = (unsigned)__builtin_amdgcn_readlane((int)es.x, jj);
            unsigned sA01 = (unsigned)__builtin_amdgcn_readlane((int)es.y, jj);
            unsigned sA23 = (unsigned)__builtin_amdgcn_readlane((int)es.z, jj);
            unsigned uB   = (unsigned)__builtin_amdgcn_readlane((int)es.x, jj + 1);
            unsigned sB01 = (unsigned)__builtin_amdgcn_readlane((int)es.y, jj + 1);
            unsigned sB23 = (unsigned)__builtin_amdgcn_readlane((int)es.z, jj + 1);
            unsigned hvA = *(const unsigned*)(hbase + uA);
            unsigned hvB = *(const unsigned*)(hbase + uB);
            f32x2 loA = __builtin_amdgcn_cvt_pk_f32_fp8(hvA, false);
            f32x2 hiA = __builtin_amdgcn_cvt_pk_f32_fp8(hvA, true);
            f32x2 loB = __builtin_amdgcn_cvt_pk_f32_fp8(hvB, false);
            f32x2 hiB = __builtin_amdgcn_cvt_pk_f32_fp8(hvB, true);
            a0 += bf2f((unsigned short)(sA01 & 0xffff)) * loA.x;
            a1 += bf2f((unsigned short)(sA01 >> 16))    * loA.y;
            a2 += bf2f((unsigned short)(sA23 & 0xffff)) * hiA.x;
            a3 += bf2f((unsigned short)(sA23 >> 16))    * hiA.y;
            a0 += bf2f((unsigned short)(sB01 & 0xffff)) * loB.x;
            a1 += bf2f((unsigned short)(sB01 >> 16))    * loB.y;
            a2 += bf2f((unsigned short)(sB23 & 0xffff)) * hiB.x;
            a3 += bf2f((unsigned short)(sB23 >> 16))    * hiB.y;
        }
        if (jj < cl) {
            unsigned uA   = (unsigned)__builtin_amdgcn_readlane((int)es.x, jj);
            unsigned sA01 = (unsigned)__builtin_amdgcn_readlane((int)es.y, jj);
            unsigned sA23 = (unsigned)__builtin_amdgcn_readlane((int)es.z, jj);
            unsigned hvA = *(const unsigned*)(hbase + uA);
            f32x2 loA = __builtin_amdgcn_cvt_pk_f32_fp8(hvA, false);
            f32x2 hiA = __builtin_amdgcn_cvt_pk_f32_fp8(hvA, true);
            a0 += bf2f((unsigned short)(sA01 & 0xffff)) * loA.x;
            a1 += bf2f((unsigned short)(sA01 >> 16))    * loA.y;
            a2 += bf2f((unsigned short)(sA23 & 0xffff)) * hiA.x;
            a3 += bf2f((unsigned short)(sA23 >> 16))    * hiA.y;
        }
    }
#pragma unroll
    for (int off = 1; off < 64; off <<= 1) {
        p0 += __shfl_xor(p0, off); p1 += __shfl_xor(p1, off);
        p2 += __shfl_xor(p2, off); p3 += __shfl_xor(p3, off);
    }
    float r0 = 1.f / (p0 + 1e-16f), r1 = 1.f / (p1 + 1e-16f);
    float r2 = 1.f / (p2 + 1e-16f), r3 = 1.f / (p3 + 1e-16f);

    unsigned hr = *(const unsigned*)(Hr8 + ((size_t)v << 8) + lane * 4);
    f32x2 rlo = __builtin_amdgcn_cvt_pk_f32_fp8(hr, false);
    f32x2 rhi = __builtin_amdgcn_cvt_pk_f32_fp8(hr, true);
    float resv = bf2f(Rres[(size_t)v * OUTD + lane]);
    float yv = conv_b[0] + (resv > 0.f ? resv : 0.f);
    float tt;
    tt = a0 * r0 + rlo.x; tt = tt > 0.f ? tt : 0.f; yv += conv_w[0] * tt;
    tt = a1 * r1 + rlo.y; tt = tt > 0.f ? tt : 0.f; yv += conv_w[1] * tt;
    tt = a2 * r2 + rhi.x; tt = tt > 0.f ? tt : 0.f; yv += conv_w[2] * tt;
    tt = a3 * r3 + rhi.y; tt = tt > 0.f ? tt : 0.f; yv += conv_w[3] * tt;
    y[(size_t)v * OUTD + lane] = yv;
}

// ============ BN tail ============
__global__ __launch_bounds__(256) void bn_partial_kernel(const float* __restrict__ y,
                                                         float* __restrict__ bnsum,
                                                         float* __restrict__ bnsumsq, int total) {
    __shared__ float smem[256];
    int t = threadIdx.x;
    size_t idx = (size_t)blockIdx.x * 256 + t;
    size_t stride = (size_t)gridDim.x * 256;
    float sum = 0.f, sq = 0.f;
    for (; idx < (size_t)total; idx += stride) {
        float v = y[idx];
        sum += v; sq += v * v;
    }
    int d = t & 63;
    smem[t] = sum; __syncthreads();
    if (t < 64) atomicAdd(bnsum + d, smem[t] + smem[t + 64] + smem[t + 128] + smem[t + 192]);
    __syncthreads();
    smem[t] = sq; __syncthreads();
    if (t < 64) atomicAdd(bnsumsq + d, smem[t] + smem[t + 64] + smem[t + 128] + smem[t + 192]);
}

__global__ void norm_kernel(const float* __restrict__ y,
                            const float* __restrict__ bnsum, const float* __restrict__ bnsumsq,
                            const float* __restrict__ gamma, const float* __restrict__ beta,
                            float* __restrict__ out, int total4, float invN) {
    int idx = blockIdx.x * blockDim.x + threadIdx.x;
    if (idx >= total4) return;
    float4 v = *(const float4*)(y + (size_t)idx * 4);
    int d = (idx * 4) & 63;
    float4 o;
#pragma unroll
    for (int k = 0; k < 4; ++k) {
        float mean = bnsum[d + k] * invN;
        float var = bnsumsq[d + k] * invN - mean * mean;
        float sc = gamma[d + k] * rsqrtf(var + BN_EPS);
        float sh = beta[d + k] - mean * sc;
        (&o.x)[k] = (&v.x)[k] * sc + sh;
    }
    *(float4*)(out + (size_t)idx * 4) = o;
}

// ============ launch ============
extern "C" void kernel_launch(void* const* d_in, const int* in_sizes, int n_in,
                              void* d_out, int out_size, void* d_ws, size_t ws_size,
                              hipStream_t stream) {
    const float* node_feats = (const float*)d_in[0];
    const float* W_fc       = (const float*)d_in[1];
    const float* attn_l     = (const float*)d_in[2];
    const float* attn_r     = (const float*)d_in[3];
    const float* gat_res_w  = (const float*)d_in[4];
    const float* gat_bias   = (const float*)d_in[5];
    const float* conv_w     = (const float*)d_in[6];
    const float* conv_b     = (const float*)d_in[7];
    const float* res_w      = (const float*)d_in[8];
    const float* res_b      = (const float*)d_in[9];
    const float* bn_gamma   = (const float*)d_in[10];
    const float* bn_beta    = (const float*)d_in[11];
    const int*   src        = (const int*)d_in[12];
    const int*   dst        = (const int*)d_in[13];

    const int N = in_sizes[0] / IN_F;
    const int E = in_sizes[12];
    const int Mtiles = (N + 63) / 64;
    const int nb = (N + 255) / 256;

    char* ws = (char*)d_ws;
    size_t off = 0;
    auto alloc = [&](size_t bytes) -> void* {
        void* p = (void*)(ws + off);
        off += (bytes + 255) & ~(size_t)255;
        return p;
    };

    // --- zero zone ---
    int*   degree  = (int*)alloc((size_t)N * 4);
    float* bnsum   = (float*)alloc(64 * 4);
    float* bnsumsq = (float*)alloc(64 * 4);
    size_t zero_bytes = off;
    // --- rest ---
    int*            rank      = (int*)alloc((size_t)E * 4);
    int*            excl      = (int*)alloc((size_t)N * 4);
    int*            blocksum  = (int*)alloc(256 * 4);
    int*            base      = (int*)alloc(256 * 4);
    uint4*          es_sorted = (uint4*)alloc((size_t)E * 16);
    unsigned short* Btg       = (unsigned short*)alloc((size_t)576 * IN_F * 2);
    unsigned char*  Hh8       = (unsigned char*)alloc((size_t)N * 256);
    unsigned char*  Hr8       = (unsigned char*)alloc((size_t)N * 256);
    unsigned short* Rres      = (unsigned short*)alloc((size_t)N * OUTD * 2);
    float*          el        = (float*)alloc((size_t)N * 4 * 4);
    float*          er        = (float*)alloc((size_t)N * 4 * 4);
    float*          y         = (float*)alloc((size_t)N * OUTD * 4);
    (void)ws_size; (void)n_in; (void)out_size;

    hipMemsetAsync(d_ws, 0, zero_bytes, stream);

    // 0. pack B weights
    k0_pack<<<(576 * 128 + 255) / 256, 256, 0, stream>>>(W_fc, gat_res_w, res_w, Btg);
    // 1. MFMA GEMM + histogram + el/er (+bias folding)
    k1_gemm<<<Mtiles + HIST_BLOCKS, 256, 0, stream>>>(node_feats, Btg, attn_l, attn_r,
                                                      gat_bias, res_b, dst, degree, rank,
                                                      Hh8, Hr8, Rres, el, er, N, E, Mtiles);
    // 2. scan
    scanA_kernel<<<nb, 256, 0, stream>>>(degree, excl, blocksum, N);
    scanB_kernel<<<1, 256, 0, stream>>>(blocksum, base, nb);
    // 3. scatter + score compute
    scatter_kernel<<<(E + 255) / 256, 256, 0, stream>>>(src, dst, rank, excl, base,
                                                        el, er, es_sorted, E);
    // 4. aggregation + epilogue
    agg_kernel<<<(N + 3) / 4, 256, 0, stream>>>(Hh8, Hr8, Rres, excl, base, es_sorted,
                                                conv_w, conv_b, y, N, E);
    // 5. BN
    bn_partial_kernel<<<512, 256, 0, stream>>>(y, bnsum, bnsumsq, N * OUTD);
    norm_kernel<<<(N * OUTD / 4 + 255) / 256, 256, 0, stream>>>(y, bnsum, bnsumsq,
                                                                bn_gamma, bn_beta, (float*)d_out,
                                                                N * OUTD / 4, 1.f / (float)N);
}